// Round 2
// baseline (1618.937 us; speedup 1.0000x reference)
//
#include <hip/hip_runtime.h>
#include <hip/hip_bf16.h>

#define T_LEN 512
#define NSTEP 511
#define H 128
#define D_IN 64
#define D_OUT 64
#define STRIDE 136   // ushorts per in-buf row: 128 + 8 pad (16B pad keeps b128 alignment, breaks bank aliasing)
#define XSTR 513     // floats per xbuf row (odd stride -> conflict-free broadcast reads)

typedef __attribute__((ext_vector_type(8))) short short8;
typedef __attribute__((ext_vector_type(4))) float f32x4;
typedef __attribute__((ext_vector_type(4))) unsigned short us4;

__device__ __forceinline__ unsigned short f2bf(float f) {
  unsigned int x = __float_as_uint(f);
  x += 0x7fffu + ((x >> 16) & 1u);   // round-to-nearest-even
  return (unsigned short)(x >> 16);
}
__device__ __forceinline__ float tanh_fast(float x) {
  float e = __expf(2.f * x);
  return 1.f - 2.f / (e + 1.f);
}
__device__ __forceinline__ float silu_f(float x) {
  return x / (1.f + __expf(-x));
}

// one [16 rows j][16 cols b] output tile over K=128: D[j][b] = sum_k W[j][k]*in[b][k] (+acc)
// wf[s]: A-frag, lane holds W[16w + (l&15)][32s + 8*(l>>4) + i]
// in-buf: bf16 [b][k] row-major, stride STRIDE ushorts
__device__ __forceinline__ f32x4 matvec(const unsigned short* buf, int l15, int lg,
                                        const short8* wf, f32x4 acc) {
  const unsigned short* base = buf + l15 * STRIDE + 8 * lg;
  short8 bf0 = *(const short8*)(base + 0);
  short8 bf1 = *(const short8*)(base + 32);
  short8 bf2 = *(const short8*)(base + 64);
  short8 bf3 = *(const short8*)(base + 96);
  acc = __builtin_amdgcn_mfma_f32_16x16x32_bf16(wf[0], bf0, acc, 0, 0, 0);
  acc = __builtin_amdgcn_mfma_f32_16x16x32_bf16(wf[1], bf1, acc, 0, 0, 0);
  acc = __builtin_amdgcn_mfma_f32_16x16x32_bf16(wf[2], bf2, acc, 0, 0, 0);
  acc = __builtin_amdgcn_mfma_f32_16x16x32_bf16(wf[3], bf3, acc, 0, 0, 0);
  return acc;
}

// write D-frag (rows jbase..jbase+3, col l15) as bf16 into in-buf [b=l15][k=j]
__device__ __forceinline__ void writev(unsigned short* buf, int l15, int jbase, f32x4 v) {
  us4 pk;
  pk.x = f2bf(v[0]); pk.y = f2bf(v[1]); pk.z = f2bf(v[2]); pk.w = f2bf(v[3]);
  *(us4*)(buf + l15 * STRIDE + jbase) = pk;
}

__global__ __launch_bounds__(512, 2) void rnnode_kernel(
    const float* __restrict__ x,     const float* __restrict__ span,
    const float* __restrict__ W_emb, const float* __restrict__ b_emb,
    const float* __restrict__ W_ih,  const float* __restrict__ b_ih,
    const float* __restrict__ W_hh,  const float* __restrict__ b_hh,
    const float* __restrict__ W1,    const float* __restrict__ b1p,
    const float* __restrict__ W2,    const float* __restrict__ b2p,
    const float* __restrict__ W_out, const float* __restrict__ b_out,
    float* __restrict__ out) {
  __shared__ __align__(16) unsigned short inbuf[2][16 * STRIDE];
  __shared__ float xbuf[16 * XSTR];
  __shared__ float dtbuf[T_LEN];

  const int tid = threadIdx.x;
  const int w   = tid >> 6;     // wave 0..7, owns j-tile [16w, 16w+16)
  const int l   = tid & 63;
  const int l15 = l & 15;       // operand lane index: A-row / B-col(b) / D-col(b)
  const int lg  = l >> 4;       // k-group
  const int b0  = blockIdx.x * 8;

  // ---- stage x (8 real rows; pad rows zeroed so pad columns stay finite) ----
  for (int i = tid; i < 8 * T_LEN; i += 512) {
    int b = i >> 9, t = i & (T_LEN - 1);
    xbuf[b * XSTR + t] = x[(b0 + b) * T_LEN + t];
  }
  for (int i = tid; i < 8 * XSTR; i += 512) xbuf[8 * XSTR + i] = 0.f;
  for (int t = tid; t < NSTEP; t += 512) dtbuf[t] = span[t + 1] - span[t];
  for (int i = tid; i < 2 * 16 * STRIDE; i += 512) ((unsigned short*)inbuf)[i] = 0;  // h0 = 0

  // ---- weights -> registers as bf16 A-frags (rows 16w + l15) ----
  short8 whhf[4], w1f[4], w2f[4];
  {
    const int row = 16 * w + l15;
#pragma unroll
    for (int s = 0; s < 4; ++s) {
      const float* p; short8 f;
      p = W_hh + row * H + 32 * s + 8 * lg;
#pragma unroll
      for (int i = 0; i < 8; ++i) f[i] = (short)f2bf(p[i]);
      whhf[s] = f;
      p = W1 + row * H + 32 * s + 8 * lg;
#pragma unroll
      for (int i = 0; i < 8; ++i) f[i] = (short)f2bf(p[i]);
      w1f[s] = f;
      p = W2 + row * H + 32 * s + 8 * lg;
#pragma unroll
      for (int i = 0; i < 8; ++i) f[i] = (short)f2bf(p[i]);
      w2f[s] = f;
    }
  }

  // ---- folded embedding + biases for D rows j = 16w + 4lg + r ----
  // e = W_ih @ W_emb ; c = W_ih @ b_emb + b_ih + b_hh
  f32x4 e_v, c_v, b1_v, b2_v;
#pragma unroll
  for (int r = 0; r < 4; ++r) {
    int j = 16 * w + 4 * lg + r;
    float e = 0.f, c = 0.f;
    const float* wr = W_ih + j * D_IN;
    for (int d = 0; d < D_IN; ++d) { float v = wr[d]; e += v * W_emb[d]; c += v * b_emb[d]; }
    e_v[r] = e; c_v[r] = c + b_ih[j] + b_hh[j];
    b1_v[r] = b1p[j]; b2_v[r] = b2p[j];
  }

  __syncthreads();

  const int jbase = 16 * w + 4 * lg;
  int cur = 0;
  for (int t = 0; t < NSTEP; ++t) {
    const float dt = dtbuf[t];
    const float xv = xbuf[l15 * XSTR + t];   // x for batch col b = l15 (0 for pad cols)
    f32x4 acc, h1v, k1v, k2v, ksv, uv, sv;

    // ---- jump: h1 = tanh(W_hh*h + x*e + c) ----
#pragma unroll
    for (int r = 0; r < 4; ++r) acc[r] = xv * e_v[r] + c_v[r];
    acc = matvec(inbuf[cur], l15, lg, whhf, acc);
#pragma unroll
    for (int r = 0; r < 4; ++r) h1v[r] = tanh_fast(acc[r]);
    writev(inbuf[cur ^ 1], l15, jbase, h1v);
    __syncthreads();

    // ---- k1 = f(h1): g = W1*h1+b1 ; s = silu(g) ----
    acc = matvec(inbuf[cur ^ 1], l15, lg, w1f, b1_v);
#pragma unroll
    for (int r = 0; r < 4; ++r) sv[r] = silu_f(acc[r]);
    writev(inbuf[cur], l15, jbase, sv);
    __syncthreads();
    // k1 = W2*s + b2 ; u1 = h1 + dt*k1/3
    k1v = matvec(inbuf[cur], l15, lg, w2f, b2_v);
#pragma unroll
    for (int r = 0; r < 4; ++r) uv[r] = h1v[r] + dt * (1.f / 3.f) * k1v[r];
    writev(inbuf[cur ^ 1], l15, jbase, uv);
    __syncthreads();

    // ---- k2 = f(u1) ----
    acc = matvec(inbuf[cur ^ 1], l15, lg, w1f, b1_v);
#pragma unroll
    for (int r = 0; r < 4; ++r) sv[r] = silu_f(acc[r]);
    writev(inbuf[cur], l15, jbase, sv);
    __syncthreads();
    k2v = matvec(inbuf[cur], l15, lg, w2f, b2_v);
#pragma unroll
    for (int r = 0; r < 4; ++r) uv[r] = h1v[r] + dt * (k2v[r] - (1.f / 3.f) * k1v[r]);
    writev(inbuf[cur ^ 1], l15, jbase, uv);
    __syncthreads();

    // ---- k3 = f(u2) ----
    acc = matvec(inbuf[cur ^ 1], l15, lg, w1f, b1_v);
#pragma unroll
    for (int r = 0; r < 4; ++r) sv[r] = silu_f(acc[r]);
    writev(inbuf[cur], l15, jbase, sv);
    __syncthreads();
    acc = matvec(inbuf[cur], l15, lg, w2f, b2_v);   // k3
#pragma unroll
    for (int r = 0; r < 4; ++r) {
      ksv[r] = k1v[r] + 3.f * (k2v[r] + acc[r]);
      uv[r]  = h1v[r] + dt * (k1v[r] - k2v[r] + acc[r]);
    }
    writev(inbuf[cur ^ 1], l15, jbase, uv);
    __syncthreads();

    // ---- k4 = f(u3); h = h1 + (k1 + 3(k2+k3) + k4)*dt/8 ----
    acc = matvec(inbuf[cur ^ 1], l15, lg, w1f, b1_v);
#pragma unroll
    for (int r = 0; r < 4; ++r) sv[r] = silu_f(acc[r]);
    writev(inbuf[cur], l15, jbase, sv);
    __syncthreads();
    acc = matvec(inbuf[cur], l15, lg, w2f, b2_v);   // k4
#pragma unroll
    for (int r = 0; r < 4; ++r) uv[r] = h1v[r] + (ksv[r] + acc[r]) * (dt * 0.125f);
    writev(inbuf[cur ^ 1], l15, jbase, uv);
    __syncthreads();

    cur ^= 1;
  }

  // ---- output: out = hT @ W_out.T + b_out (64 outputs -> waves 0..3) ----
  if (w < 4) {
    short8 wof[4];
    const int row = 16 * w + l15;
#pragma unroll
    for (int s = 0; s < 4; ++s) {
      const float* p = W_out + row * H + 32 * s + 8 * lg;
      short8 f;
#pragma unroll
      for (int i = 0; i < 8; ++i) f[i] = (short)f2bf(p[i]);
      wof[s] = f;
    }
    f32x4 acc;
#pragma unroll
    for (int r = 0; r < 4; ++r) acc[r] = b_out[16 * w + 4 * lg + r];
    acc = matvec(inbuf[cur], l15, lg, wof, acc);
    if (l15 < 8) {
#pragma unroll
      for (int r = 0; r < 4; ++r)
        out[(b0 + l15) * D_OUT + 16 * w + 4 * lg + r] = acc[r];
    }
  }
}

extern "C" void kernel_launch(void* const* d_in, const int* in_sizes, int n_in,
                              void* d_out, int out_size, void* d_ws, size_t ws_size,
                              hipStream_t stream) {
  (void)in_sizes; (void)n_in; (void)ws_size; (void)d_ws; (void)out_size;
  const float* x     = (const float*)d_in[0];
  const float* span  = (const float*)d_in[1];
  const float* W_emb = (const float*)d_in[2];
  const float* b_emb = (const float*)d_in[3];
  const float* W_ih  = (const float*)d_in[4];
  const float* b_ih  = (const float*)d_in[5];
  const float* W_hh  = (const float*)d_in[6];
  const float* b_hh  = (const float*)d_in[7];
  const float* W1    = (const float*)d_in[8];
  const float* b1    = (const float*)d_in[9];
  const float* W2    = (const float*)d_in[10];
  const float* b2    = (const float*)d_in[11];
  const float* W_out = (const float*)d_in[12];
  const float* b_out = (const float*)d_in[13];
  float* out = (float*)d_out;

  rnnode_kernel<<<dim3(256), dim3(512), 0, stream>>>(
      x, span, W_emb, b_emb, W_ih, b_ih, W_hh, b_hh,
      W1, b1, W2, b2, W_out, b_out, out);
}